// Round 1
// baseline (286.095 us; speedup 1.0000x reference)
//
#include <hip/hip_runtime.h>
#include <hip/hip_bf16.h>

typedef unsigned short u16;
typedef unsigned int u32;
typedef __attribute__((ext_vector_type(4))) float f32x4;
typedef __attribute__((ext_vector_type(8))) short s16x8;
typedef __attribute__((ext_vector_type(4))) unsigned short u16x4;
typedef __attribute__((ext_vector_type(8))) unsigned short u16x8;

#define LRELU(x) ((x) > 0.f ? (x) : 0.01f * (x))

__device__ __forceinline__ u16 f2bf(float x) {
    u32 u = __float_as_uint(x);
    return (u16)((u + 0x7fffu + ((u >> 16) & 1u)) >> 16);
}
__device__ __forceinline__ float bf2f(u16 h) { return __uint_as_float((u32)h << 16); }

// ---------------- prep: w1 = W*a1, w2 = W*a2, Wt hi/lo transpose-split -------
__global__ void k_prep(const float* __restrict__ W, const float* __restrict__ a,
                       u16* __restrict__ Wt_hi, u16* __restrict__ Wt_lo,
                       float* __restrict__ w1, float* __restrict__ w2) {
    int i = blockIdx.x, t = threadIdx.x;
    float x = W[i * 256 + t];
    float p1 = x * a[t];
    float p2 = x * a[256 + t];
#pragma unroll
    for (int off = 1; off < 64; off <<= 1) {
        p1 += __shfl_xor(p1, off);
        p2 += __shfl_xor(p2, off);
    }
    __shared__ float s1[4], s2[4];
    if ((t & 63) == 0) { s1[t >> 6] = p1; s2[t >> 6] = p2; }
    __syncthreads();
    if (t == 0) {
        w1[i] = s1[0] + s1[1] + s1[2] + s1[3];
        w2[i] = s2[0] + s2[1] + s2[2] + s2[3];
    }
    // transpose column i -> Wt row i, split hi/lo
    float y = W[t * 256 + i];
    u16 hi = f2bf(y);
    Wt_hi[i * 256 + t] = hi;
    Wt_lo[i * 256 + t] = f2bf(y - bf2f(hi));
}

// ---------------- f1/f2: exact fp32 row dots of inp with w1/w2 --------------
__global__ void k_f(const float* __restrict__ inp, const float* __restrict__ w1,
                    const float* __restrict__ w2, float* __restrict__ f1,
                    float* __restrict__ f2) {
    __shared__ float sw1[256], sw2[256];
    int t = threadIdx.x;
    sw1[t] = w1[t];
    sw2[t] = w2[t];
    __syncthreads();
    int wv = t >> 6, l = t & 63;
    f32x4 c1 = *(const f32x4*)&sw1[l * 4];
    f32x4 c2 = *(const f32x4*)&sw2[l * 4];
    for (int it = 0; it < 16; ++it) {
        int row = blockIdx.x * 64 + wv * 16 + it;
        f32x4 v = *(const f32x4*)&inp[row * 256 + l * 4];
        float d1 = v.x * c1.x + v.y * c1.y + v.z * c1.z + v.w * c1.w;
        float d2 = v.x * c2.x + v.y * c2.y + v.z * c2.z + v.w * c2.w;
#pragma unroll
        for (int off = 1; off < 64; off <<= 1) {
            d1 += __shfl_xor(d1, off);
            d2 += __shfl_xor(d2, off);
        }
        if (l == 0) { f1[row] = d1; f2[row] = d2; }
    }
}

// ---------------- per-batch max of f2 ---------------------------------------
__global__ void k_m(const float* __restrict__ f2, float* __restrict__ Mb) {
    int b = blockIdx.x, t = threadIdx.x;
    float m = -1e30f;
#pragma unroll
    for (int j = 0; j < 4; ++j) m = fmaxf(m, f2[b * 1024 + t + j * 256]);
#pragma unroll
    for (int off = 1; off < 64; off <<= 1) m = fmaxf(m, __shfl_xor(m, off));
    __shared__ float s[4];
    if ((t & 63) == 0) s[t >> 6] = m;
    __syncthreads();
    if (t == 0) Mb[b] = fmaxf(fmaxf(s[0], s[1]), fmaxf(s[2], s[3]));
}

// ---------------- GEMM1: h = inp @ W  (3-term bf16 split, ~fp32-exact) ------
// writes h transposed+split: ht_hi/ht_lo [b][f][n] bf16
__global__ __launch_bounds__(256) void k_gemm1(const float* __restrict__ inp,
                                               const u16* __restrict__ Wt_hi,
                                               const u16* __restrict__ Wt_lo,
                                               u16* __restrict__ ht_hi,
                                               u16* __restrict__ ht_lo) {
    __shared__ __align__(16) char lds[40960];
    u16* Ah = (u16*)lds;            // 64x32
    u16* Al = Ah + 2048;            // 64x32
    u16* Bh = Al + 2048;            // 256x32
    u16* Bl = Bh + 8192;            // 256x32
    int t = threadIdx.x;
    int r0 = blockIdx.x * 64;
    int w = t >> 6, l = t & 63, lr = l & 15, lk = l >> 4;

    f32x4 acc[4][4];
#pragma unroll
    for (int i = 0; i < 4; ++i)
#pragma unroll
        for (int j = 0; j < 4; ++j)
#pragma unroll
            for (int r = 0; r < 4; ++r) acc[i][j][r] = 0.f;

    for (int kt = 0; kt < 8; ++kt) {
        int k0 = kt * 32;
        __syncthreads();
        // stage A tile 64x32 fp32 -> hi/lo bf16, swizzled
#pragma unroll
        for (int s = 0; s < 2; ++s) {
            int q = t + 256 * s;  // 0..511 float4s
            int row = q >> 3;
            int kc = (q & 7) * 4;
            f32x4 v = *(const f32x4*)&inp[(r0 + row) * 256 + k0 + kc];
            u16x4 hv, lv;
#pragma unroll
            for (int j = 0; j < 4; ++j) {
                float x = v[j];
                u16 hi = f2bf(x);
                hv[j] = hi;
                lv[j] = f2bf(x - bf2f(hi));
            }
            int eo = row * 32 + (kc ^ ((row & 3) << 3));
            *(u16x4*)&Ah[eo] = hv;
            *(u16x4*)&Al[eo] = lv;
        }
        // stage B (Wt slice) 256x32, swizzled
        {
            const u16x8* sh = (const u16x8*)&Wt_hi[t * 256 + k0];
            const u16x8* sl = (const u16x8*)&Wt_lo[t * 256 + k0];
#pragma unroll
            for (int c = 0; c < 4; ++c) {
                int eo = t * 32 + ((c ^ (t & 3)) * 8);
                *(u16x8*)&Bh[eo] = sh[c];
                *(u16x8*)&Bl[eo] = sl[c];
            }
        }
        __syncthreads();
        s16x8 ah[4], al[4], bh[4], bl[4];
#pragma unroll
        for (int it = 0; it < 4; ++it) {
            int row = it * 16 + lr;
            int eo = row * 32 + ((lk ^ (row & 3)) * 8);
            ah[it] = *(const s16x8*)&Ah[eo];
            al[it] = *(const s16x8*)&Al[eo];
        }
#pragma unroll
        for (int ci = 0; ci < 4; ++ci) {
            int f = w * 64 + ci * 16 + lr;
            int eo = f * 32 + ((lk ^ (f & 3)) * 8);
            bh[ci] = *(const s16x8*)&Bh[eo];
            bl[ci] = *(const s16x8*)&Bl[eo];
        }
#pragma unroll
        for (int it = 0; it < 4; ++it)
#pragma unroll
            for (int ci = 0; ci < 4; ++ci) {
                acc[it][ci] = __builtin_amdgcn_mfma_f32_16x16x32_bf16(ah[it], bh[ci], acc[it][ci], 0, 0, 0);
                acc[it][ci] = __builtin_amdgcn_mfma_f32_16x16x32_bf16(ah[it], bl[ci], acc[it][ci], 0, 0, 0);
                acc[it][ci] = __builtin_amdgcn_mfma_f32_16x16x32_bf16(al[it], bh[ci], acc[it][ci], 0, 0, 0);
            }
    }
    // epilogue: LDS transpose -> ht_hi/ht_lo [b][f][n] (coalesced 128B rows)
    int b = r0 >> 10, n0 = r0 & 1023;
    float* tr = (float*)lds;  // [64][65]
    for (int cg = 0; cg < 4; ++cg) {
        __syncthreads();
        if (w == cg) {
#pragma unroll
            for (int it = 0; it < 4; ++it)
#pragma unroll
                for (int ci = 0; ci < 4; ++ci) {
                    int colL = ci * 16 + lr;
                    int rowb = it * 16 + lk * 4;
#pragma unroll
                    for (int r = 0; r < 4; ++r) tr[(rowb + r) * 65 + colL] = acc[it][ci][r];
                }
        }
        __syncthreads();
        int fl = t >> 2, np = (t & 3) * 16;
        u16x8 hv[2], lv[2];
#pragma unroll
        for (int i = 0; i < 16; ++i) {
            float x = tr[(np + i) * 65 + fl];
            u16 hi = f2bf(x);
            hv[i >> 3][i & 7] = hi;
            lv[i >> 3][i & 7] = f2bf(x - bf2f(hi));
        }
        size_t basei = (size_t)(b * 256 + cg * 64 + fl) * 1024 + n0 + np;
        *(u16x8*)&ht_hi[basei] = hv[0];
        *(u16x8*)&ht_hi[basei + 8] = hv[1];
        *(u16x8*)&ht_lo[basei] = lv[0];
        *(u16x8*)&ht_lo[basei + 8] = lv[1];
    }
}

// ---------------- attention: softmax(leaky(f1+f2)) @ h, elu -----------------
__global__ __launch_bounds__(256) void k_attn(const u16* __restrict__ ht_hi,
                                              const u16* __restrict__ ht_lo,
                                              const float* __restrict__ f1,
                                              const float* __restrict__ f2,
                                              const float* __restrict__ Mb,
                                              float* __restrict__ out) {
    __shared__ u16 Hh[256 * 64];
    __shared__ u16 Hl[256 * 64];
    int t = threadIdx.x, w = t >> 6, l = t & 63, lr = l & 15, lk = l >> 4;
    int bid = blockIdx.x;
    int b = bid >> 4, i0 = (bid & 15) * 64;
    float Mv = Mb[b];
    float f1v[4], mi[4];
#pragma unroll
    for (int it = 0; it < 4; ++it) {
        float x = f1[b * 1024 + i0 + it * 16 + lr];
        f1v[it] = x;
        float e = x + Mv;
        mi[it] = LRELU(e);
    }
    f32x4 acc[4][4];
#pragma unroll
    for (int i = 0; i < 4; ++i)
#pragma unroll
        for (int j = 0; j < 4; ++j)
#pragma unroll
            for (int r = 0; r < 4; ++r) acc[i][j][r] = 0.f;
    float lsum[4] = {0.f, 0.f, 0.f, 0.f};

    for (int jt = 0; jt < 16; ++jt) {
        int j0 = jt * 64;
        __syncthreads();
        {
            const u16x8* sh = (const u16x8*)&ht_hi[(size_t)(b * 256 + t) * 1024 + j0];
            const u16x8* sl = (const u16x8*)&ht_lo[(size_t)(b * 256 + t) * 1024 + j0];
#pragma unroll
            for (int c = 0; c < 8; ++c) {
                int eo = t * 64 + ((c ^ (t & 7)) * 8);
                *(u16x8*)&Hh[eo] = sh[c];
                *(u16x8*)&Hl[eo] = sl[c];
            }
        }
        __syncthreads();
#pragma unroll
        for (int ks = 0; ks < 2; ++ks) {
            f32x4 f2a = *(const f32x4*)&f2[b * 1024 + j0 + ks * 32 + lk * 8];
            f32x4 f2b_ = *(const f32x4*)&f2[b * 1024 + j0 + ks * 32 + lk * 8 + 4];
            s16x8 pf[4];
#pragma unroll
            for (int it = 0; it < 4; ++it) {
                u16x8 pv;
#pragma unroll
                for (int jj = 0; jj < 8; ++jj) {
                    float fv = (jj < 4) ? f2a[jj] : f2b_[jj - 4];
                    float e = f1v[it] + fv;
                    e = LRELU(e);
                    float p = __expf(e - mi[it]);
                    lsum[it] += p;
                    pv[jj] = f2bf(p);
                }
                pf[it] = *(s16x8*)&pv;
            }
#pragma unroll
            for (int ci = 0; ci < 4; ++ci) {
                int f = w * 64 + ci * 16 + lr;
                int eo = f * 64 + (((ks * 4) + lk) ^ (f & 7)) * 8;
                s16x8 bh = *(const s16x8*)&Hh[eo];
                s16x8 bl = *(const s16x8*)&Hl[eo];
#pragma unroll
                for (int it = 0; it < 4; ++it) {
                    acc[it][ci] = __builtin_amdgcn_mfma_f32_16x16x32_bf16(pf[it], bh, acc[it][ci], 0, 0, 0);
                    acc[it][ci] = __builtin_amdgcn_mfma_f32_16x16x32_bf16(pf[it], bl, acc[it][ci], 0, 0, 0);
                }
            }
        }
    }
#pragma unroll
    for (int it = 0; it < 4; ++it) {
        lsum[it] += __shfl_xor(lsum[it], 16);
        lsum[it] += __shfl_xor(lsum[it], 32);
    }
#pragma unroll
    for (int it = 0; it < 4; ++it) {
        float lrow[4];
#pragma unroll
        for (int r = 0; r < 4; ++r) lrow[r] = __shfl(lsum[it], lk * 4 + r, 16);
#pragma unroll
        for (int ci = 0; ci < 4; ++ci) {
            int col = w * 64 + ci * 16 + lr;
            int rowg = b * 1024 + i0 + it * 16 + lk * 4;
#pragma unroll
            for (int r = 0; r < 4; ++r) {
                float v = acc[it][ci][r] / lrow[r];
                v = v > 0.f ? v : (__expf(v) - 1.f);
                out[(size_t)(rowg + r) * 256 + col] = v;
            }
        }
    }
}

extern "C" void kernel_launch(void* const* d_in, const int* in_sizes, int n_in,
                              void* d_out, int out_size, void* d_ws, size_t ws_size,
                              hipStream_t stream) {
    const float* inp = (const float*)d_in[0];
    const float* W = (const float*)d_in[1];
    const float* a = (const float*)d_in[2];
    float* out = (float*)d_out;

    char* ws = (char*)d_ws;
    u16* ht_hi = (u16*)(ws + 0);            // 16,777,216 B
    u16* ht_lo = (u16*)(ws + 16777216);     // 16,777,216 B
    u16* Wt_hi = (u16*)(ws + 33554432);     // 131,072 B
    u16* Wt_lo = (u16*)(ws + 33685504);     // 131,072 B
    float* w1 = (float*)(ws + 33816576);    // 1,024 B
    float* w2 = (float*)(ws + 33817600);    // 1,024 B
    float* f1 = (float*)(ws + 33818624);    // 131,072 B
    float* f2 = (float*)(ws + 33949696);    // 131,072 B
    float* Mb = (float*)(ws + 34080768);    // 128 B

    k_prep<<<256, 256, 0, stream>>>(W, a, Wt_hi, Wt_lo, w1, w2);
    k_f<<<512, 256, 0, stream>>>(inp, w1, w2, f1, f2);
    k_m<<<32, 256, 0, stream>>>(f2, Mb);
    k_gemm1<<<512, 256, 0, stream>>>(inp, Wt_hi, Wt_lo, ht_hi, ht_lo);
    k_attn<<<512, 256, 0, stream>>>(ht_hi, ht_lo, f1, f2, Mb, out);
}

// Round 2
// 204.099 us; speedup vs baseline: 1.4017x; 1.4017x over previous
//
#include <hip/hip_runtime.h>
#include <hip/hip_bf16.h>

typedef unsigned short u16;
typedef unsigned int u32;
typedef __attribute__((ext_vector_type(4))) float f32x4;
typedef __attribute__((ext_vector_type(8))) short s16x8;
typedef __attribute__((ext_vector_type(4))) unsigned short u16x4;
typedef __attribute__((ext_vector_type(8))) unsigned short u16x8;

#define LRELU(x) ((x) > 0.f ? (x) : 0.01f * (x))

static __device__ __forceinline__ u16 f2bf(float x) {
    u32 u = __float_as_uint(x);
    return (u16)((u + 0x7fffu + ((u >> 16) & 1u)) >> 16);
}
static __device__ __forceinline__ float bf2f(u16 h) { return __uint_as_float((u32)h << 16); }

// ---------------- prep: w1 = W*a1, w2 = W*a2, Wt hi/lo transpose-split -------
__global__ void k_prep(const float* __restrict__ W, const float* __restrict__ a,
                       u16* __restrict__ Wt_hi, u16* __restrict__ Wt_lo,
                       float* __restrict__ w1, float* __restrict__ w2) {
    int i = blockIdx.x, t = threadIdx.x;
    float x = W[i * 256 + t];
    float p1 = x * a[t];
    float p2 = x * a[256 + t];
#pragma unroll
    for (int off = 1; off < 64; off <<= 1) {
        p1 += __shfl_xor(p1, off);
        p2 += __shfl_xor(p2, off);
    }
    __shared__ float s1[4], s2[4];
    if ((t & 63) == 0) { s1[t >> 6] = p1; s2[t >> 6] = p2; }
    __syncthreads();
    if (t == 0) {
        w1[i] = s1[0] + s1[1] + s1[2] + s1[3];
        w2[i] = s2[0] + s2[1] + s2[2] + s2[3];
    }
    // transpose column i -> Wt row i, split hi/lo
    float y = W[t * 256 + i];
    u16 hi = f2bf(y);
    Wt_hi[i * 256 + t] = hi;
    Wt_lo[i * 256 + t] = f2bf(y - bf2f(hi));
}

// ---------------- f1/f2: exact fp32 row dots of inp with w1/w2 --------------
__global__ void k_f(const float* __restrict__ inp, const float* __restrict__ w1,
                    const float* __restrict__ w2, float* __restrict__ f1,
                    float* __restrict__ f2) {
    __shared__ float sw1[256], sw2[256];
    int t = threadIdx.x;
    sw1[t] = w1[t];
    sw2[t] = w2[t];
    __syncthreads();
    int wv = t >> 6, l = t & 63;
    f32x4 c1 = *(const f32x4*)&sw1[l * 4];
    f32x4 c2 = *(const f32x4*)&sw2[l * 4];
    for (int it = 0; it < 16; ++it) {
        int row = blockIdx.x * 64 + wv * 16 + it;
        f32x4 v = *(const f32x4*)&inp[row * 256 + l * 4];
        float d1 = v.x * c1.x + v.y * c1.y + v.z * c1.z + v.w * c1.w;
        float d2 = v.x * c2.x + v.y * c2.y + v.z * c2.z + v.w * c2.w;
#pragma unroll
        for (int off = 1; off < 64; off <<= 1) {
            d1 += __shfl_xor(d1, off);
            d2 += __shfl_xor(d2, off);
        }
        if (l == 0) { f1[row] = d1; f2[row] = d2; }
    }
}

// ---------------- per-batch max of f2 ---------------------------------------
__global__ void k_m(const float* __restrict__ f2, float* __restrict__ Mb) {
    int b = blockIdx.x, t = threadIdx.x;
    float m = -1e30f;
#pragma unroll
    for (int j = 0; j < 4; ++j) m = fmaxf(m, f2[b * 1024 + t + j * 256]);
#pragma unroll
    for (int off = 1; off < 64; off <<= 1) m = fmaxf(m, __shfl_xor(m, off));
    __shared__ float s[4];
    if ((t & 63) == 0) s[t >> 6] = m;
    __syncthreads();
    if (t == 0) Mb[b] = fmaxf(fmaxf(s[0], s[1]), fmaxf(s[2], s[3]));
}

// ---------------- k_h: ht = (inp @ W)^T, hi/lo bf16, 3-term split -----------
// D[f][n] = mfma(A = Wt rows f, B = inp rows n). No LDS, no barriers.
__global__ __launch_bounds__(256, 2) void k_h(const float* __restrict__ inp,
                                              const u16* __restrict__ Wt_hi,
                                              const u16* __restrict__ Wt_lo,
                                              u16* __restrict__ ht_hi,
                                              u16* __restrict__ ht_lo) {
    int t = threadIdx.x, w = t >> 6, l = t & 63, lr = l & 15, lk = l >> 4;
    int blkf = blockIdx.x >> 7;   // 0..3   (64 f rows each)
    int blkn = blockIdx.x & 127;  // 0..127 (256 n rows each)
    int f0 = blkf * 64;
    int n0 = blkn * 256;

    f32x4 acc[4][4];
#pragma unroll
    for (int i = 0; i < 4; ++i)
#pragma unroll
        for (int j = 0; j < 4; ++j)
#pragma unroll
            for (int r = 0; r < 4; ++r) acc[i][j][r] = 0.f;

    for (int kt = 0; kt < 8; ++kt) {
        int k0 = kt * 32 + lk * 8;
        s16x8 ah[4], al[4];
#pragma unroll
        for (int it = 0; it < 4; ++it) {
            int f = f0 + it * 16 + lr;
            ah[it] = *(const s16x8*)&Wt_hi[f * 256 + k0];
            al[it] = *(const s16x8*)&Wt_lo[f * 256 + k0];
        }
        s16x8 bh[4], bl[4];
#pragma unroll
        for (int ci = 0; ci < 4; ++ci) {
            int n = n0 + w * 64 + ci * 16 + lr;
            f32x4 v0 = *(const f32x4*)&inp[n * 256 + k0];
            f32x4 v1 = *(const f32x4*)&inp[n * 256 + k0 + 4];
            u16x8 hv, lv;
#pragma unroll
            for (int j = 0; j < 4; ++j) {
                u16 h0 = f2bf(v0[j]);
                hv[j] = h0;
                lv[j] = f2bf(v0[j] - bf2f(h0));
                u16 h1 = f2bf(v1[j]);
                hv[j + 4] = h1;
                lv[j + 4] = f2bf(v1[j] - bf2f(h1));
            }
            bh[ci] = *(s16x8*)&hv;
            bl[ci] = *(s16x8*)&lv;
        }
#pragma unroll
        for (int it = 0; it < 4; ++it)
#pragma unroll
            for (int ci = 0; ci < 4; ++ci) {
                acc[it][ci] = __builtin_amdgcn_mfma_f32_16x16x32_bf16(ah[it], bh[ci], acc[it][ci], 0, 0, 0);
                acc[it][ci] = __builtin_amdgcn_mfma_f32_16x16x32_bf16(ah[it], bl[ci], acc[it][ci], 0, 0, 0);
                acc[it][ci] = __builtin_amdgcn_mfma_f32_16x16x32_bf16(al[it], bh[ci], acc[it][ci], 0, 0, 0);
            }
    }
    int bb = n0 >> 10, nb0 = n0 & 1023;
#pragma unroll
    for (int it = 0; it < 4; ++it)
#pragma unroll
        for (int ci = 0; ci < 4; ++ci) {
            int col = nb0 + w * 64 + ci * 16 + lr;
#pragma unroll
            for (int r = 0; r < 4; ++r) {
                int F = f0 + it * 16 + lk * 4 + r;
                float x = acc[it][ci][r];
                u16 hh = f2bf(x);
                size_t o = (size_t)(bb * 256 + F) * 1024 + col;
                ht_hi[o] = hh;
                ht_lo[o] = f2bf(x - bf2f(hh));
            }
        }
}

// ---------------- attention: softmax(leaky(f1+f2)) @ h, elu -----------------
// Wave w computes P only for its 16-row tile (A-frag layout), shares via LDS.
// H fragments read directly from global (L2-resident). 1 barrier / 128-j chunk.
__global__ __launch_bounds__(256, 2) void k_attn(const u16* __restrict__ ht_hi,
                                                 const u16* __restrict__ ht_lo,
                                                 const float* __restrict__ f1,
                                                 const float* __restrict__ f2,
                                                 const float* __restrict__ Mb,
                                                 float* __restrict__ out) {
    __shared__ float sf2[1024];
    __shared__ u16 P[2][4][4][512];  // [buf][it][s][lane*8] bf16
    __shared__ float rs[64];
    int t = threadIdx.x, w = t >> 6, l = t & 63, lr = l & 15, lk = l >> 4;
    // XCD-aware swizzle: XCD x handles batches 4x..4x+3 (L2 locality for ht[b])
    int g = blockIdx.x;
    int xcd = g & 7, idx = g >> 3;
    int b = xcd * 4 + (idx >> 4);
    int i0 = (idx & 15) * 64;

    *(f32x4*)&sf2[t * 4] = *(const f32x4*)&f2[b * 1024 + t * 4];
    float Mv = Mb[b];
    int rowP = i0 + w * 16 + lr;
    float f1v = f1[b * 1024 + rowP];
    float miv = LRELU(f1v + Mv);
    float lsum = 0.f;
    const u16* Hh = ht_hi + (size_t)b * 256 * 1024;
    const u16* Hl = ht_lo + (size_t)b * 256 * 1024;

    auto computeP = [&](int cc2, int buf2) {
#pragma unroll
        for (int s = 0; s < 4; ++s) {
            int jb = cc2 * 128 + s * 32 + lk * 8;
            f32x4 fa = *(const f32x4*)&sf2[jb];
            f32x4 fb = *(const f32x4*)&sf2[jb + 4];
            u16x8 pv;
#pragma unroll
            for (int jj = 0; jj < 8; ++jj) {
                float fv = (jj < 4) ? fa[jj] : fb[jj - 4];
                float e = LRELU(f1v + fv);
                float p = __expf(e - miv);
                lsum += p;
                pv[jj] = f2bf(p);
            }
            *(u16x8*)&P[buf2][w][s][l * 8] = pv;
        }
    };

    f32x4 acc[4][4];
#pragma unroll
    for (int i = 0; i < 4; ++i)
#pragma unroll
        for (int j = 0; j < 4; ++j)
#pragma unroll
            for (int r = 0; r < 4; ++r) acc[i][j][r] = 0.f;

    __syncthreads();  // sf2 visible
    computeP(0, 0);

    for (int cc = 0; cc < 8; ++cc) {
        __syncthreads();  // P(cc) writes visible; buf[(cc+1)&1] readers done
        if (cc < 7) computeP(cc + 1, (cc + 1) & 1);
        int buf = cc & 1;
#pragma unroll
        for (int s = 0; s < 4; ++s) {
            int jcol = cc * 128 + s * 32 + lk * 8;
            s16x8 pf[4];
#pragma unroll
            for (int it = 0; it < 4; ++it) pf[it] = *(const s16x8*)&P[buf][it][s][l * 8];
#pragma unroll
            for (int ci = 0; ci < 4; ++ci) {
                int f = w * 64 + ci * 16 + lr;
                s16x8 bh = *(const s16x8*)&Hh[(size_t)f * 1024 + jcol];
                s16x8 bl = *(const s16x8*)&Hl[(size_t)f * 1024 + jcol];
#pragma unroll
                for (int it = 0; it < 4; ++it) {
                    acc[it][ci] = __builtin_amdgcn_mfma_f32_16x16x32_bf16(pf[it], bh, acc[it][ci], 0, 0, 0);
                    acc[it][ci] = __builtin_amdgcn_mfma_f32_16x16x32_bf16(pf[it], bl, acc[it][ci], 0, 0, 0);
                }
            }
        }
    }

    // row sums: reduce over the 4 lk lanes sharing a row, share via LDS
    lsum += __shfl_xor(lsum, 16);
    lsum += __shfl_xor(lsum, 32);
    if (l < 16) rs[w * 16 + lr] = lsum;
    __syncthreads();

#pragma unroll
    for (int it = 0; it < 4; ++it) {
        f32x4 sums = *(const f32x4*)&rs[it * 16 + lk * 4];
#pragma unroll
        for (int ci = 0; ci < 4; ++ci) {
            int col = w * 64 + ci * 16 + lr;
            int rowg = b * 1024 + i0 + it * 16 + lk * 4;
#pragma unroll
            for (int r = 0; r < 4; ++r) {
                float v = acc[it][ci][r] / sums[r];
                v = v > 0.f ? v : (__expf(v) - 1.f);
                out[(size_t)(rowg + r) * 256 + col] = v;
            }
        }
    }
}

extern "C" void kernel_launch(void* const* d_in, const int* in_sizes, int n_in,
                              void* d_out, int out_size, void* d_ws, size_t ws_size,
                              hipStream_t stream) {
    const float* inp = (const float*)d_in[0];
    const float* W = (const float*)d_in[1];
    const float* a = (const float*)d_in[2];
    float* out = (float*)d_out;

    char* ws = (char*)d_ws;
    u16* ht_hi = (u16*)(ws + 0);            // 16,777,216 B
    u16* ht_lo = (u16*)(ws + 16777216);     // 16,777,216 B
    u16* Wt_hi = (u16*)(ws + 33554432);     // 131,072 B
    u16* Wt_lo = (u16*)(ws + 33685504);     // 131,072 B
    float* w1 = (float*)(ws + 33816576);    // 1,024 B
    float* w2 = (float*)(ws + 33817600);    // 1,024 B
    float* f1 = (float*)(ws + 33818624);    // 131,072 B
    float* f2 = (float*)(ws + 33949696);    // 131,072 B
    float* Mb = (float*)(ws + 34080768);    // 128 B

    k_prep<<<256, 256, 0, stream>>>(W, a, Wt_hi, Wt_lo, w1, w2);
    k_f<<<512, 256, 0, stream>>>(inp, w1, w2, f1, f2);
    k_m<<<32, 256, 0, stream>>>(f2, Mb);
    k_h<<<512, 256, 0, stream>>>(inp, Wt_hi, Wt_lo, ht_hi, ht_lo);
    k_attn<<<512, 256, 0, stream>>>(ht_hi, ht_lo, f1, f2, Mb, out);
}